// Round 14
// baseline (428.015 us; speedup 1.0000x reference)
//
#include <hip/hip_runtime.h>
#include <stdint.h>

#define BB 8
#define TTN 4096
#define CCH 32
#define KEEP_LT9 3435974144u   // keep iff bits < this (uniform < 0.8f)

typedef __attribute__((ext_vector_type(8))) short bf16x8;
typedef __attribute__((ext_vector_type(4))) float f32x4;

union B8 { uint32_t u[4]; uint4 q; bf16x8 v; };

__device__ __forceinline__ uint32_t cvt_pk_bf16(float lo, float hi) {
    uint32_t d;
    asm("v_cvt_pk_bf16_f32 %0, %1, %2" : "=v"(d) : "v"(lo), "v"(hi));
    return d;
}

// bare v_exp_f32: 2^x (scores kept in log2 domain)
__device__ __forceinline__ float exp2_fast(float x) {
    float d;
    asm("v_exp_f32 %0, %1" : "=v"(d) : "v"(x));
    return d;
}

// rotl via funnel-shift: 1 VALU inst
__device__ __forceinline__ uint32_t rotl32(uint32_t x, int r) {
    return __builtin_amdgcn_alignbit(x, x, 32 - r);
}

// 4 interleaved threefry2x32 chains (explicit ILP; key (0,42); out = o0^o1)
__device__ __forceinline__ void threefry4(uint32_t i0, uint32_t i1, uint32_t i2, uint32_t i3,
                                          uint32_t& o0, uint32_t& o1, uint32_t& o2, uint32_t& o3) {
    const uint32_t K2 = 42u ^ 0x1BD11BDAu;
    uint32_t a0 = 0u, a1 = 0u, a2 = 0u, a3 = 0u;
    uint32_t b0 = i0 + 42u, b1 = i1 + 42u, b2 = i2 + 42u, b3 = i3 + 42u;
#define R4(r)                                                                  \
    { a0 += b0; a1 += b1; a2 += b2; a3 += b3;                                  \
      b0 = rotl32(b0, (r)); b1 = rotl32(b1, (r));                              \
      b2 = rotl32(b2, (r)); b3 = rotl32(b3, (r));                              \
      b0 ^= a0; b1 ^= a1; b2 ^= a2; b3 ^= a3; }
#define INJ(da, db)                                                            \
    { a0 += (da); a1 += (da); a2 += (da); a3 += (da);                          \
      b0 += (db); b1 += (db); b2 += (db); b3 += (db); }
    R4(13) R4(15) R4(26) R4(6)
    INJ(42u, K2 + 1u)
    R4(17) R4(29) R4(16) R4(24)
    INJ(K2, 2u)
    R4(13) R4(15) R4(26) R4(6)
    INJ(0u, 42u + 3u)
    R4(17) R4(29) R4(16) R4(24)
    INJ(42u, K2 + 4u)
    R4(13) R4(15) R4(26) R4(6)
    INJ(K2, 5u)
#undef R4
#undef INJ
    o0 = a0 ^ b0; o1 = a1 ^ b1; o2 = a2 ^ b2; o3 = a3 ^ b3;
}

// ---------------- projections: Q fp32 (log2-scaled), K bf16, V bf16 TRANSPOSED ----------------
__global__ __launch_bounds__(256) void proj_qkv(const float* __restrict__ x,
                                                const float* __restrict__ Wq,
                                                const float* __restrict__ Wk,
                                                const float* __restrict__ Wv,
                                                float* __restrict__ Qf,
                                                uint16_t* __restrict__ Kb,
                                                uint16_t* __restrict__ Vt) {
    __shared__ float sW[3][CCH * CCH];
    __shared__ uint16_t vs[256][34];
    const int tid = threadIdx.x;
    for (int i = tid; i < CCH * CCH; i += 256) {
        sW[0][i] = Wq[i]; sW[1][i] = Wk[i]; sW[2][i] = Wv[i];
    }
    __syncthreads();
    const int row = blockIdx.x * 256 + tid;     // b*T + t
    const float4* xp = reinterpret_cast<const float4*>(x + (size_t)row * CCH);
    float xr[CCH];
    #pragma unroll
    for (int i = 0; i < 8; ++i) {
        float4 t4 = xp[i];
        xr[4*i] = t4.x; xr[4*i+1] = t4.y; xr[4*i+2] = t4.z; xr[4*i+3] = t4.w;
    }
    const float scale = 0.2550348616f;          // log2(e)/sqrt(32)
    #pragma unroll
    for (int mtx = 0; mtx < 3; ++mtx) {
        float o[CCH];
        #pragma unroll
        for (int d = 0; d < CCH; ++d) {
            float s0 = 0.f, s1 = 0.f, s2 = 0.f, s3 = 0.f;
            #pragma unroll
            for (int c = 0; c < CCH; c += 4) {
                s0 += xr[c]   * sW[mtx][d*CCH + c];
                s1 += xr[c+1] * sW[mtx][d*CCH + c+1];
                s2 += xr[c+2] * sW[mtx][d*CCH + c+2];
                s3 += xr[c+3] * sW[mtx][d*CCH + c+3];
            }
            o[d] = (s0 + s1) + (s2 + s3);
            if (mtx == 0) o[d] *= scale;
        }
        if (mtx == 0) {
            float4* op = reinterpret_cast<float4*>(Qf + (size_t)row * CCH);
            #pragma unroll
            for (int i = 0; i < 8; ++i)
                op[i] = make_float4(o[4*i], o[4*i+1], o[4*i+2], o[4*i+3]);
        } else if (mtx == 1) {
            uint32_t dw[16];
            #pragma unroll
            for (int k = 0; k < 16; ++k) dw[k] = cvt_pk_bf16(o[2*k], o[2*k+1]);
            uint4* kp = reinterpret_cast<uint4*>((char*)Kb + (size_t)row * 64);
            #pragma unroll
            for (int q = 0; q < 4; ++q)
                kp[q] = make_uint4(dw[4*q], dw[4*q+1], dw[4*q+2], dw[4*q+3]);
        } else {
            #pragma unroll
            for (int k = 0; k < 16; ++k)
                *reinterpret_cast<uint32_t*>(&vs[tid][2*k]) = cvt_pk_bf16(o[2*k], o[2*k+1]);
        }
    }
    __syncthreads();
    const int b = blockIdx.x >> 4, seg = blockIdx.x & 15;
    const int d = tid >> 3, part = tid & 7;
    uint32_t dw[16];
    #pragma unroll
    for (int k = 0; k < 16; ++k) {
        const uint32_t lo = vs[part*32 + 2*k][d];
        const uint32_t hi = vs[part*32 + 2*k + 1][d];
        dw[k] = lo | (hi << 16);
    }
    uint16_t* dst = Vt + (size_t)b * (CCH * TTN) + (size_t)d * TTN + seg * 256 + part * 32;
    uint4* dp = reinterpret_cast<uint4*>(dst);
    #pragma unroll
    for (int q = 0; q < 4; ++q)
        dp[q] = make_uint4(dw[4*q], dw[4*q+1], dw[4*q+2], dw[4*q+3]);
}

// ---------------- MFMA flash attention, fused threefry, UNIFORM blocks ----------------
// 2048 blocks of 256 thr, all equal work: block (b, p, h, seg) runs
// leg0 = (tile p, thalf h) and leg1 = (tile 127-p, thalf 1-h), windows of
// parity `seg` only. nwin(p,h) + nwin(127-p,1-h) == 33 for every pair ->
// per-block work = 16 or 17 windows -> exact 8 blocks/CU co-resident, no drain.
// Per-seg partial (m, l, acc) stored to workspace; merge_out combines.
__global__ __launch_bounds__(256, 8) void attn_mfma(const float* __restrict__ Qf,
                                                    const uint16_t* __restrict__ Kb,
                                                    const uint16_t* __restrict__ Vt,
                                                    float* __restrict__ pws) {
    __shared__ __align__(16) char smem[9984];

    const int j = blockIdx.x;
    const int b = j & 7;                        // XCD-local batch
    const int p = (j >> 3) & 63;
    const int h = (j >> 9) & 1;
    const int seg = (j >> 10) & 1;

    const int w = threadIdx.x >> 6;             // wave = s-slice 0..3
    const int lane = threadIdx.x & 63;
    const int tl = lane & 15;
    const int g = lane >> 4;
    const int slb = w * 32;

    const char* Kbb = (const char*)Kb + (size_t)b * TTN * 64;
    const char* Vbb = (const char*)Vt + (size_t)b * CCH * TTN * 2;

    float* mxex = reinterpret_cast<float*>(smem) + (w << 6);             // [64] f32
    uint32_t* pex = reinterpret_cast<uint32_t*>(smem + 1024) + (w << 8); // [256] u32

    #pragma unroll 1
    for (int leg = 0; leg < 2; ++leg) {
        const int tile = leg ? (127 - p) : p;
        const int th = leg ? (1 - h) : h;
        const int tbase = tile * 32 + th * 16;
        const int t_g = tbase + tl;
        const int nwin = ((tbase + 15) >> 7) + 1;
        const uint32_t idxb = ((uint32_t)b << 24) | ((uint32_t)t_g << 12);

        const float* qrow = Qf + ((size_t)b * TTN + t_g) * CCH + g * 8;
        const float4 qa = *reinterpret_cast<const float4*>(qrow);
        const float4 qb = *reinterpret_cast<const float4*>(qrow + 4);
        B8 qf;
        qf.u[0] = cvt_pk_bf16(qa.x, qa.y); qf.u[1] = cvt_pk_bf16(qa.z, qa.w);
        qf.u[2] = cvt_pk_bf16(qb.x, qb.y); qf.u[3] = cvt_pk_bf16(qb.z, qb.w);

        f32x4 acc0 = {0.f,0.f,0.f,0.f}, acc1 = {0.f,0.f,0.f,0.f};
        float m = -1e30f, l = 0.f;

        B8 kaA, kcA, vaA, vcA, kaB, kcB, vaB, vcB;
        uint32_t rA[8], rB[8];

#define LOADF(KA, KC, VA, VC, S0)                                              \
    {                                                                          \
        const int srow = (S0) + slb;                                           \
        KA.q = *reinterpret_cast<const uint4*>(Kbb + (size_t)(srow + tl) * 64 + g * 16); \
        KC.q = *reinterpret_cast<const uint4*>(Kbb + (size_t)(srow + 16 + tl) * 64 + g * 16); \
        VA.q = *reinterpret_cast<const uint4*>(Vbb + (size_t)tl * 8192 + (size_t)(srow + g * 8) * 2); \
        VC.q = *reinterpret_cast<const uint4*>(Vbb + (size_t)(16 + tl) * 8192 + (size_t)(srow + g * 8) * 2); \
    }
#define TF8(R, S0)                                                             \
    {                                                                          \
        const uint32_t ib = idxb | (uint32_t)((S0) + slb + 4 * g);             \
        threefry4(ib,       ib + 1u,  ib + 2u,  ib + 3u,  R[0], R[1], R[2], R[3]); \
        threefry4(ib + 16u, ib + 17u, ib + 18u, ib + 19u, R[4], R[5], R[6], R[7]); \
    }
#define SMAXPV(KA, KC, VA, VC, R, S0, ISTAIL)                                  \
    {                                                                          \
        const f32x4 zz = {0.f,0.f,0.f,0.f};                                    \
        f32x4 d0 = __builtin_amdgcn_mfma_f32_16x16x32_bf16(KA.v, qf.v, zz, 0, 0, 0); \
        f32x4 d1 = __builtin_amdgcn_mfma_f32_16x16x32_bf16(KC.v, qf.v, zz, 0, 0, 0); \
        const bool istail_ = (ISTAIL);                                         \
        if (istail_) {                                                         \
            const int sv = (S0) + slb + 4 * g;                                 \
            d0.x = (sv + 0  <= t_g) ? d0.x : -1e30f;                           \
            d0.y = (sv + 1  <= t_g) ? d0.y : -1e30f;                           \
            d0.z = (sv + 2  <= t_g) ? d0.z : -1e30f;                           \
            d0.w = (sv + 3  <= t_g) ? d0.w : -1e30f;                           \
            d1.x = (sv + 16 <= t_g) ? d1.x : -1e30f;                           \
            d1.y = (sv + 17 <= t_g) ? d1.y : -1e30f;                           \
            d1.z = (sv + 18 <= t_g) ? d1.z : -1e30f;                           \
            d1.w = (sv + 19 <= t_g) ? d1.w : -1e30f;                           \
        }                                                                      \
        float mx = fmaxf(fmaxf(fmaxf(d0.x, d0.y), fmaxf(d0.z, d0.w)),          \
                         fmaxf(fmaxf(d1.x, d1.y), fmaxf(d1.z, d1.w)));         \
        mxex[(tl << 2) + g] = mx;                                              \
        const float4 m4 = *reinterpret_cast<const float4*>(mxex + (tl << 2));  \
        mx = fmaxf(fmaxf(m4.x, m4.y), fmaxf(m4.z, m4.w));                      \
        const bool up = mx > m + 11.5f;                                        \
        const float corr = up ? exp2_fast(m - mx) : 1.0f;                      \
        m = up ? mx : m;                                                       \
        l *= corr; acc0 *= corr; acc1 *= corr;                                 \
        float p0 = exp2_fast(d0.x - m), p1 = exp2_fast(d0.y - m);              \
        float p2 = exp2_fast(d0.z - m), p3 = exp2_fast(d0.w - m);              \
        float p4 = exp2_fast(d1.x - m), p5 = exp2_fast(d1.y - m);              \
        float p6 = exp2_fast(d1.z - m), p7 = exp2_fast(d1.w - m);              \
        if (istail_) {                                                         \
            const float alive = ((S0) + slb <= t_g) ? 1.0f : 0.0f;             \
            p0 *= alive; p1 *= alive; p2 *= alive; p3 *= alive;                \
            p4 *= alive; p5 *= alive; p6 *= alive; p7 *= alive;                \
        }                                                                      \
        l += ((p0 + p1) + (p2 + p3)) + ((p4 + p5) + (p6 + p7));                \
        const float q0 = (R[0] < KEEP_LT9) ? p0 : 0.f;                         \
        const float q1 = (R[1] < KEEP_LT9) ? p1 : 0.f;                         \
        const float q2 = (R[2] < KEEP_LT9) ? p2 : 0.f;                         \
        const float q3 = (R[3] < KEEP_LT9) ? p3 : 0.f;                         \
        const float q4 = (R[4] < KEEP_LT9) ? p4 : 0.f;                         \
        const float q5 = (R[5] < KEEP_LT9) ? p5 : 0.f;                         \
        const float q6 = (R[6] < KEEP_LT9) ? p6 : 0.f;                         \
        const float q7 = (R[7] < KEEP_LT9) ? p7 : 0.f;                         \
        const uint32_t k00 = cvt_pk_bf16(q0, q1), k01 = cvt_pk_bf16(q2, q3);   \
        const uint32_t k10 = cvt_pk_bf16(q4, q5), k11 = cvt_pk_bf16(q6, q7);   \
        *reinterpret_cast<uint4*>(pex + (lane << 2)) = make_uint4(k00, k01, k10, k11); \
        const int srcA4 = (((g & 1) ? 32 : 0) + tl) << 2;                      \
        const int sel = (g >= 2) ? 2 : 0;                                      \
        const uint2 lo2 = *reinterpret_cast<const uint2*>(pex + srcA4 + sel);  \
        const uint2 hi2 = *reinterpret_cast<const uint2*>(pex + srcA4 + 64 + sel); \
        B8 pf;                                                                 \
        pf.u[0] = lo2.x; pf.u[1] = lo2.y; pf.u[2] = hi2.x; pf.u[3] = hi2.y;    \
        acc0 = __builtin_amdgcn_mfma_f32_16x16x32_bf16(VA.v, pf.v, acc0, 0, 0, 0); \
        acc1 = __builtin_amdgcn_mfma_f32_16x16x32_bf16(VC.v, pf.v, acc1, 0, 0, 0); \
    }

        // windows win = seg, seg+2, ... < nwin; A/B alternating pipeline (no copies)
        int win = seg;
        if (win < nwin) {
            LOADF(kaA, kcA, vaA, vcA, win << 7)
            TF8(rA, win << 7)
            while (true) {
                int nxt = win + 2;
                if (nxt < nwin) {
                    LOADF(kaB, kcB, vaB, vcB, nxt << 7)
                    TF8(rB, nxt << 7)
                    SMAXPV(kaA, kcA, vaA, vcA, rA, win << 7, win == nwin - 1)
                } else {
                    SMAXPV(kaA, kcA, vaA, vcA, rA, win << 7, win == nwin - 1)
                    break;
                }
                win = nxt; nxt = win + 2;
                if (nxt < nwin) {
                    LOADF(kaA, kcA, vaA, vcA, nxt << 7)
                    TF8(rA, nxt << 7)
                    SMAXPV(kaB, kcB, vaB, vcB, rB, win << 7, win == nwin - 1)
                } else {
                    SMAXPV(kaB, kcB, vaB, vcB, rB, win << 7, win == nwin - 1)
                    break;
                }
                win = nxt;
            }
        }
#undef SMAXPV
#undef TF8
#undef LOADF

        // deferred l-reduce over the 4 g-lanes of each t
        l += __shfl_xor(l, 16);
        l += __shfl_xor(l, 32);

        // in-block merge of the 4 s-slices, then store per-seg partial
#define SLOT(S) reinterpret_cast<float*>(smem + 5120 + (S) * 2432)
#define PUBLISH(SB)                                                            \
    {                                                                          \
        float* sb = (SB);                                                      \
        *reinterpret_cast<float4*>(sb + tl * 36 + 4 * g)      = make_float4(acc0.x, acc0.y, acc0.z, acc0.w); \
        *reinterpret_cast<float4*>(sb + tl * 36 + 16 + 4 * g) = make_float4(acc1.x, acc1.y, acc1.z, acc1.w); \
        if (g == 0) { sb[576 + 2 * tl] = m; sb[577 + 2 * tl] = l; }            \
    }
#define CONSUME(SB)                                                            \
    {                                                                          \
        const float* sb = (SB);                                                \
        const float m2 = sb[576 + 2 * tl], l2 = sb[577 + 2 * tl];              \
        const float4 x0 = *reinterpret_cast<const float4*>(sb + tl * 36 + 4 * g); \
        const float4 x1 = *reinterpret_cast<const float4*>(sb + tl * 36 + 16 + 4 * g); \
        const float mn = fmaxf(m, m2);                                         \
        const float ca = exp2_fast(m - mn), cb = exp2_fast(m2 - mn);           \
        l = l * ca + l2 * cb;                                                  \
        acc0.x = acc0.x * ca + x0.x * cb; acc0.y = acc0.y * ca + x0.y * cb;    \
        acc0.z = acc0.z * ca + x0.z * cb; acc0.w = acc0.w * ca + x0.w * cb;    \
        acc1.x = acc1.x * ca + x1.x * cb; acc1.y = acc1.y * ca + x1.y * cb;    \
        acc1.z = acc1.z * ca + x1.z * cb; acc1.w = acc1.w * ca + x1.w * cb;    \
        m = mn;                                                                \
    }
        __syncthreads();                        // LDS quiet before merge reuse
        if (w >= 2) PUBLISH(SLOT(w - 2))
        __syncthreads();
        if (w < 2) CONSUME(SLOT(w))
        __syncthreads();
        if (w == 1) PUBLISH(SLOT(0))
        __syncthreads();
        if (w == 0) {
            CONSUME(SLOT(0))
            // store per-seg partial: [group][seg][16 t][34]
            const int gi = (b << 8) + (tile << 1) + th;
            float* dst = pws + (((size_t)gi * 2 + seg) * 16 + tl) * 34;
            if (g == 0) { dst[0] = m; dst[1] = l; }
            *reinterpret_cast<float4*>(dst + 2 + 4 * g) =
                make_float4(acc0.x, acc0.y, acc0.z, acc0.w);
            *reinterpret_cast<float4*>(dst + 18 + 4 * g) =
                make_float4(acc1.x, acc1.y, acc1.z, acc1.w);
        }
        __syncthreads();
#undef SLOT
#undef PUBLISH
#undef CONSUME
    }
}

// ---------------- merge the two seg-partials per 16-row group, write out ----------------
__global__ __launch_bounds__(256) void merge_out(const float* __restrict__ pws,
                                                 float* __restrict__ out) {
    const int gw = (blockIdx.x << 2) + (threadIdx.x >> 6);  // group 0..2047
    const int lane = threadIdx.x & 63;
    const int tl = lane & 15, g = lane >> 4;
    const int b = gw >> 8, tile = (gw & 255) >> 1, th = gw & 1;

    const float* s0 = pws + (((size_t)gw * 2 + 0) * 16 + tl) * 34;
    const float* s1 = pws + (((size_t)gw * 2 + 1) * 16 + tl) * 34;
    const float m0 = s0[0], l0 = s0[1], m1 = s1[0], l1 = s1[1];
    const float mn = fmaxf(m0, m1);
    const float c0 = exp2_fast(m0 - mn);        // m=-1e30 (empty seg) -> 0
    const float c1 = exp2_fast(m1 - mn);
    const float inv = 1.0f / (0.8f * (l0 * c0 + l1 * c1));

    const float4 a0 = *reinterpret_cast<const float4*>(s0 + 2 + 4 * g);
    const float4 b0 = *reinterpret_cast<const float4*>(s1 + 2 + 4 * g);
    const float4 a1 = *reinterpret_cast<const float4*>(s0 + 18 + 4 * g);
    const float4 b1 = *reinterpret_cast<const float4*>(s1 + 18 + 4 * g);

    float* orow = out + (((size_t)b * TTN) + tile * 32 + th * 16 + tl) * CCH;
    *reinterpret_cast<float4*>(orow + 4 * g) = make_float4(
        (a0.x * c0 + b0.x * c1) * inv, (a0.y * c0 + b0.y * c1) * inv,
        (a0.z * c0 + b0.z * c1) * inv, (a0.w * c0 + b0.w * c1) * inv);
    *reinterpret_cast<float4*>(orow + 16 + 4 * g) = make_float4(
        (a1.x * c0 + b1.x * c1) * inv, (a1.y * c0 + b1.y * c1) * inv,
        (a1.z * c0 + b1.z * c1) * inv, (a1.w * c0 + b1.w * c1) * inv);
}

extern "C" void kernel_launch(void* const* d_in, const int* in_sizes, int n_in,
                              void* d_out, int out_size, void* d_ws, size_t ws_size,
                              hipStream_t stream) {
    const float* x  = (const float*)d_in[0];
    const float* Wq = (const float*)d_in[1];
    const float* Wk = (const float*)d_in[2];
    const float* Wv = (const float*)d_in[3];
    float* outp = (float*)d_out;

    // workspace: Qf 4MiB | Kb 2MiB | Vt 2MiB | partials ~8.9MiB
    float*    Qf  = (float*)d_ws;
    uint16_t* Kb  = (uint16_t*)((char*)d_ws + 4194304);
    uint16_t* Vt  = (uint16_t*)((char*)d_ws + 6291456);
    float*    pws = (float*)((char*)d_ws + 8388608);

    proj_qkv<<<(BB * TTN) / 256, 256, 0, stream>>>(x, Wq, Wk, Wv, Qf, Kb, Vt);
    attn_mfma<<<2048, 256, 0, stream>>>(Qf, Kb, Vt, pws);
    merge_out<<<512, 256, 0, stream>>>(pws, outp);
}

// Round 15
// 166.000 us; speedup vs baseline: 2.5784x; 2.5784x over previous
//
#include <hip/hip_runtime.h>
#include <stdint.h>

#define BB 8
#define TTN 4096
#define CCH 32
#define KEEP_LT9 3435974144u   // keep iff bits < this (uniform < 0.8f)

typedef __attribute__((ext_vector_type(8))) short bf16x8;
typedef __attribute__((ext_vector_type(4))) float f32x4;

union B8 { uint32_t u[4]; uint4 q; bf16x8 v; };

__device__ __forceinline__ uint32_t cvt_pk_bf16(float lo, float hi) {
    uint32_t d;
    asm("v_cvt_pk_bf16_f32 %0, %1, %2" : "=v"(d) : "v"(lo), "v"(hi));
    return d;
}

// bare v_exp_f32: 2^x (scores kept in log2 domain)
__device__ __forceinline__ float exp2_fast(float x) {
    float d;
    asm("v_exp_f32 %0, %1" : "=v"(d) : "v"(x));
    return d;
}

// rotl via funnel-shift: 1 VALU inst
__device__ __forceinline__ uint32_t rotl32(uint32_t x, int r) {
    return __builtin_amdgcn_alignbit(x, x, 32 - r);
}

// 4 interleaved threefry2x32 chains (explicit ILP; key (0,42); out = o0^o1)
__device__ __forceinline__ void threefry4(uint32_t i0, uint32_t i1, uint32_t i2, uint32_t i3,
                                          uint32_t& o0, uint32_t& o1, uint32_t& o2, uint32_t& o3) {
    const uint32_t K2 = 42u ^ 0x1BD11BDAu;
    uint32_t a0 = 0u, a1 = 0u, a2 = 0u, a3 = 0u;
    uint32_t b0 = i0 + 42u, b1 = i1 + 42u, b2 = i2 + 42u, b3 = i3 + 42u;
#define R4(r)                                                                  \
    { a0 += b0; a1 += b1; a2 += b2; a3 += b3;                                  \
      b0 = rotl32(b0, (r)); b1 = rotl32(b1, (r));                              \
      b2 = rotl32(b2, (r)); b3 = rotl32(b3, (r));                              \
      b0 ^= a0; b1 ^= a1; b2 ^= a2; b3 ^= a3; }
#define INJ(da, db)                                                            \
    { a0 += (da); a1 += (da); a2 += (da); a3 += (da);                          \
      b0 += (db); b1 += (db); b2 += (db); b3 += (db); }
    R4(13) R4(15) R4(26) R4(6)
    INJ(42u, K2 + 1u)
    R4(17) R4(29) R4(16) R4(24)
    INJ(K2, 2u)
    R4(13) R4(15) R4(26) R4(6)
    INJ(0u, 42u + 3u)
    R4(17) R4(29) R4(16) R4(24)
    INJ(42u, K2 + 4u)
    R4(13) R4(15) R4(26) R4(6)
    INJ(K2, 5u)
#undef R4
#undef INJ
    o0 = a0 ^ b0; o1 = a1 ^ b1; o2 = a2 ^ b2; o3 = a3 ^ b3;
}

// ---------------- projections: Q fp32 (log2-scaled), K bf16, V bf16 TRANSPOSED ----------------
__global__ __launch_bounds__(256) void proj_qkv(const float* __restrict__ x,
                                                const float* __restrict__ Wq,
                                                const float* __restrict__ Wk,
                                                const float* __restrict__ Wv,
                                                float* __restrict__ Qf,
                                                uint16_t* __restrict__ Kb,
                                                uint16_t* __restrict__ Vt) {
    __shared__ float sW[3][CCH * CCH];
    __shared__ uint16_t vs[256][34];
    const int tid = threadIdx.x;
    for (int i = tid; i < CCH * CCH; i += 256) {
        sW[0][i] = Wq[i]; sW[1][i] = Wk[i]; sW[2][i] = Wv[i];
    }
    __syncthreads();
    const int row = blockIdx.x * 256 + tid;     // b*T + t
    const float4* xp = reinterpret_cast<const float4*>(x + (size_t)row * CCH);
    float xr[CCH];
    #pragma unroll
    for (int i = 0; i < 8; ++i) {
        float4 t4 = xp[i];
        xr[4*i] = t4.x; xr[4*i+1] = t4.y; xr[4*i+2] = t4.z; xr[4*i+3] = t4.w;
    }
    const float scale = 0.2550348616f;          // log2(e)/sqrt(32)
    #pragma unroll
    for (int mtx = 0; mtx < 3; ++mtx) {
        float o[CCH];
        #pragma unroll
        for (int d = 0; d < CCH; ++d) {
            float s0 = 0.f, s1 = 0.f, s2 = 0.f, s3 = 0.f;
            #pragma unroll
            for (int c = 0; c < CCH; c += 4) {
                s0 += xr[c]   * sW[mtx][d*CCH + c];
                s1 += xr[c+1] * sW[mtx][d*CCH + c+1];
                s2 += xr[c+2] * sW[mtx][d*CCH + c+2];
                s3 += xr[c+3] * sW[mtx][d*CCH + c+3];
            }
            o[d] = (s0 + s1) + (s2 + s3);
            if (mtx == 0) o[d] *= scale;
        }
        if (mtx == 0) {
            float4* op = reinterpret_cast<float4*>(Qf + (size_t)row * CCH);
            #pragma unroll
            for (int i = 0; i < 8; ++i)
                op[i] = make_float4(o[4*i], o[4*i+1], o[4*i+2], o[4*i+3]);
        } else if (mtx == 1) {
            uint32_t dw[16];
            #pragma unroll
            for (int k = 0; k < 16; ++k) dw[k] = cvt_pk_bf16(o[2*k], o[2*k+1]);
            uint4* kp = reinterpret_cast<uint4*>((char*)Kb + (size_t)row * 64);
            #pragma unroll
            for (int q = 0; q < 4; ++q)
                kp[q] = make_uint4(dw[4*q], dw[4*q+1], dw[4*q+2], dw[4*q+3]);
        } else {
            #pragma unroll
            for (int k = 0; k < 16; ++k)
                *reinterpret_cast<uint32_t*>(&vs[tid][2*k]) = cvt_pk_bf16(o[2*k], o[2*k+1]);
        }
    }
    __syncthreads();
    const int b = blockIdx.x >> 4, seg = blockIdx.x & 15;
    const int d = tid >> 3, part = tid & 7;
    uint32_t dw[16];
    #pragma unroll
    for (int k = 0; k < 16; ++k) {
        const uint32_t lo = vs[part*32 + 2*k][d];
        const uint32_t hi = vs[part*32 + 2*k + 1][d];
        dw[k] = lo | (hi << 16);
    }
    uint16_t* dst = Vt + (size_t)b * (CCH * TTN) + (size_t)d * TTN + seg * 256 + part * 32;
    uint4* dp = reinterpret_cast<uint4*>(dst);
    #pragma unroll
    for (int q = 0; q < 4; ++q)
        dp[q] = make_uint4(dw[4*q], dw[4*q+1], dw[4*q+2], dw[4*q+3]);
}

// ---------------- MFMA flash attention, fused threefry, UNIFORM blocks, single-buffer ----------------
// 2048 blocks of 256 thr, all equal work: block (b, p, h, seg) runs
// leg0 = (tile p, thalf h) and leg1 = (tile 127-p, thalf 1-h), windows of
// parity `seg` only; nwinA + nwinB == 33 for every pair -> 16/17 windows/block.
// SINGLE-buffered window body (R12-style): live set ~45 VGPR, fits the 64-reg
// cap of (256,8) with no spill -> 8 uniform blocks/CU co-resident, no drain.
__global__ __launch_bounds__(256, 8) void attn_mfma(const float* __restrict__ Qf,
                                                    const uint16_t* __restrict__ Kb,
                                                    const uint16_t* __restrict__ Vt,
                                                    float* __restrict__ pws) {
    __shared__ __align__(16) char smem[9984];

    const int j = blockIdx.x;
    const int b = j & 7;                        // XCD-local batch
    const int p = (j >> 3) & 63;
    const int h = (j >> 9) & 1;
    const int seg = (j >> 10) & 1;

    const int w = threadIdx.x >> 6;             // wave = s-slice 0..3
    const int lane = threadIdx.x & 63;
    const int tl = lane & 15;
    const int g = lane >> 4;
    const int slb = w * 32;

    const char* Kbb = (const char*)Kb + (size_t)b * TTN * 64;
    const char* Vbb = (const char*)Vt + (size_t)b * CCH * TTN * 2;

    float* mxex = reinterpret_cast<float*>(smem) + (w << 6);             // [64] f32
    uint32_t* pex = reinterpret_cast<uint32_t*>(smem + 1024) + (w << 8); // [256] u32

    #pragma unroll 1
    for (int leg = 0; leg < 2; ++leg) {
        const int tile = leg ? (127 - p) : p;
        const int th = leg ? (1 - h) : h;
        const int tbase = tile * 32 + th * 16;
        const int t_g = tbase + tl;
        const int nwin = ((tbase + 15) >> 7) + 1;
        const uint32_t idxb = ((uint32_t)b << 24) | ((uint32_t)t_g << 12);

        const float* qrow = Qf + ((size_t)b * TTN + t_g) * CCH + g * 8;
        const float4 qa = *reinterpret_cast<const float4*>(qrow);
        const float4 qb = *reinterpret_cast<const float4*>(qrow + 4);
        B8 qf;
        qf.u[0] = cvt_pk_bf16(qa.x, qa.y); qf.u[1] = cvt_pk_bf16(qa.z, qa.w);
        qf.u[2] = cvt_pk_bf16(qb.x, qb.y); qf.u[3] = cvt_pk_bf16(qb.z, qb.w);

        f32x4 acc0 = {0.f,0.f,0.f,0.f}, acc1 = {0.f,0.f,0.f,0.f};
        float m = -1e30f, l = 0.f;

        #pragma unroll 1
        for (int win = seg; win < nwin; win += 2) {
            const int s0 = win << 7;
            const int srow = s0 + slb;
            // fragment loads (direct global; full-line coalesced; L2-resident)
            B8 ka, kc, va, vc, pf;
            ka.q = *reinterpret_cast<const uint4*>(Kbb + (size_t)(srow + tl) * 64 + g * 16);
            kc.q = *reinterpret_cast<const uint4*>(Kbb + (size_t)(srow + 16 + tl) * 64 + g * 16);
            va.q = *reinterpret_cast<const uint4*>(Vbb + (size_t)tl * 8192 + (size_t)(srow + g * 8) * 2);
            vc.q = *reinterpret_cast<const uint4*>(Vbb + (size_t)(16 + tl) * 8192 + (size_t)(srow + g * 8) * 2);
            // threefry (584 indep int-VALU: hides the load latency)
            const uint32_t ib = idxb | (uint32_t)(srow + 4 * g);
            uint32_t r0, r1, r2, r3, r4, r5, r6, r7;
            threefry4(ib,       ib + 1u,  ib + 2u,  ib + 3u,  r0, r1, r2, r3);
            threefry4(ib + 16u, ib + 17u, ib + 18u, ib + 19u, r4, r5, r6, r7);

            const f32x4 zz = {0.f,0.f,0.f,0.f};
            f32x4 d0 = __builtin_amdgcn_mfma_f32_16x16x32_bf16(ka.v, qf.v, zz, 0, 0, 0);
            f32x4 d1 = __builtin_amdgcn_mfma_f32_16x16x32_bf16(kc.v, qf.v, zz, 0, 0, 0);
            const bool istail = (win == nwin - 1);
            if (istail) {
                const int sv = srow + 4 * g;
                d0.x = (sv + 0  <= t_g) ? d0.x : -1e30f;
                d0.y = (sv + 1  <= t_g) ? d0.y : -1e30f;
                d0.z = (sv + 2  <= t_g) ? d0.z : -1e30f;
                d0.w = (sv + 3  <= t_g) ? d0.w : -1e30f;
                d1.x = (sv + 16 <= t_g) ? d1.x : -1e30f;
                d1.y = (sv + 17 <= t_g) ? d1.y : -1e30f;
                d1.z = (sv + 18 <= t_g) ? d1.z : -1e30f;
                d1.w = (sv + 19 <= t_g) ? d1.w : -1e30f;
            }
            float mx = fmaxf(fmaxf(fmaxf(d0.x, d0.y), fmaxf(d0.z, d0.w)),
                             fmaxf(fmaxf(d1.x, d1.y), fmaxf(d1.z, d1.w)));
            mxex[(tl << 2) + g] = mx;                    // same-wave LDS m-reduce
            const float4 m4 = *reinterpret_cast<const float4*>(mxex + (tl << 2));
            mx = fmaxf(fmaxf(m4.x, m4.y), fmaxf(m4.z, m4.w));
            const bool up = mx > m + 11.5f;              // deferred-max, log2 units
            const float corr = up ? exp2_fast(m - mx) : 1.0f;
            m = up ? mx : m;
            l *= corr; acc0 *= corr; acc1 *= corr;
            float p0 = exp2_fast(d0.x - m), p1 = exp2_fast(d0.y - m);
            float p2 = exp2_fast(d0.z - m), p3 = exp2_fast(d0.w - m);
            float p4 = exp2_fast(d1.x - m), p5 = exp2_fast(d1.y - m);
            float p6 = exp2_fast(d1.z - m), p7 = exp2_fast(d1.w - m);
            if (istail) {
                const float alive = (srow <= t_g) ? 1.0f : 0.0f;
                p0 *= alive; p1 *= alive; p2 *= alive; p3 *= alive;
                p4 *= alive; p5 *= alive; p6 *= alive; p7 *= alive;
            }
            l += ((p0 + p1) + (p2 + p3)) + ((p4 + p5) + (p6 + p7));
            const float q0 = (r0 < KEEP_LT9) ? p0 : 0.f;
            const float q1 = (r1 < KEEP_LT9) ? p1 : 0.f;
            const float q2 = (r2 < KEEP_LT9) ? p2 : 0.f;
            const float q3 = (r3 < KEEP_LT9) ? p3 : 0.f;
            const float q4 = (r4 < KEEP_LT9) ? p4 : 0.f;
            const float q5 = (r5 < KEEP_LT9) ? p5 : 0.f;
            const float q6 = (r6 < KEEP_LT9) ? p6 : 0.f;
            const float q7 = (r7 < KEEP_LT9) ? p7 : 0.f;
            const uint32_t k00 = cvt_pk_bf16(q0, q1), k01 = cvt_pk_bf16(q2, q3);
            const uint32_t k10 = cvt_pk_bf16(q4, q5), k11 = cvt_pk_bf16(q6, q7);
            *reinterpret_cast<uint4*>(pex + (lane << 2)) = make_uint4(k00, k01, k10, k11);
            const int srcA4 = (((g & 1) ? 32 : 0) + tl) << 2;
            const int sel = (g >= 2) ? 2 : 0;
            const uint2 lo2 = *reinterpret_cast<const uint2*>(pex + srcA4 + sel);
            const uint2 hi2 = *reinterpret_cast<const uint2*>(pex + srcA4 + 64 + sel);
            pf.u[0] = lo2.x; pf.u[1] = lo2.y; pf.u[2] = hi2.x; pf.u[3] = hi2.y;
            acc0 = __builtin_amdgcn_mfma_f32_16x16x32_bf16(va.v, pf.v, acc0, 0, 0, 0);
            acc1 = __builtin_amdgcn_mfma_f32_16x16x32_bf16(vc.v, pf.v, acc1, 0, 0, 0);
        }

        // deferred l-reduce over the 4 g-lanes of each t
        l += __shfl_xor(l, 16);
        l += __shfl_xor(l, 32);

        // in-block merge of the 4 s-slices, then store per-seg partial
#define SLOT(S) reinterpret_cast<float*>(smem + 5120 + (S) * 2432)
#define PUBLISH(SB)                                                            \
    {                                                                          \
        float* sb = (SB);                                                      \
        *reinterpret_cast<float4*>(sb + tl * 36 + 4 * g)      = make_float4(acc0.x, acc0.y, acc0.z, acc0.w); \
        *reinterpret_cast<float4*>(sb + tl * 36 + 16 + 4 * g) = make_float4(acc1.x, acc1.y, acc1.z, acc1.w); \
        if (g == 0) { sb[576 + 2 * tl] = m; sb[577 + 2 * tl] = l; }            \
    }
#define CONSUME(SB)                                                            \
    {                                                                          \
        const float* sb = (SB);                                                \
        const float m2 = sb[576 + 2 * tl], l2 = sb[577 + 2 * tl];              \
        const float4 x0 = *reinterpret_cast<const float4*>(sb + tl * 36 + 4 * g); \
        const float4 x1 = *reinterpret_cast<const float4*>(sb + tl * 36 + 16 + 4 * g); \
        const float mn = fmaxf(m, m2);                                         \
        const float ca = exp2_fast(m - mn), cb = exp2_fast(m2 - mn);           \
        l = l * ca + l2 * cb;                                                  \
        acc0.x = acc0.x * ca + x0.x * cb; acc0.y = acc0.y * ca + x0.y * cb;    \
        acc0.z = acc0.z * ca + x0.z * cb; acc0.w = acc0.w * ca + x0.w * cb;    \
        acc1.x = acc1.x * ca + x1.x * cb; acc1.y = acc1.y * ca + x1.y * cb;    \
        acc1.z = acc1.z * ca + x1.z * cb; acc1.w = acc1.w * ca + x1.w * cb;    \
        m = mn;                                                                \
    }
        __syncthreads();                        // LDS quiet before merge reuse
        if (w >= 2) PUBLISH(SLOT(w - 2))
        __syncthreads();
        if (w < 2) CONSUME(SLOT(w))
        __syncthreads();
        if (w == 1) PUBLISH(SLOT(0))
        __syncthreads();
        if (w == 0) {
            CONSUME(SLOT(0))
            // store per-seg partial: [group][seg][16 t][34]
            const int gi = (b << 8) + (tile << 1) + th;
            float* dst = pws + (((size_t)gi * 2 + seg) * 16 + tl) * 34;
            if (g == 0) { dst[0] = m; dst[1] = l; }
            *reinterpret_cast<float4*>(dst + 2 + 4 * g) =
                make_float4(acc0.x, acc0.y, acc0.z, acc0.w);
            *reinterpret_cast<float4*>(dst + 18 + 4 * g) =
                make_float4(acc1.x, acc1.y, acc1.z, acc1.w);
        }
        __syncthreads();
#undef SLOT
#undef PUBLISH
#undef CONSUME
    }
}

// ---------------- merge the two seg-partials per 16-row group, write out ----------------
__global__ __launch_bounds__(256) void merge_out(const float* __restrict__ pws,
                                                 float* __restrict__ out) {
    const int gw = (blockIdx.x << 2) + (threadIdx.x >> 6);  // group 0..2047
    const int lane = threadIdx.x & 63;
    const int tl = lane & 15, g = lane >> 4;
    const int b = gw >> 8, tile = (gw & 255) >> 1, th = gw & 1;

    const float* s0 = pws + (((size_t)gw * 2 + 0) * 16 + tl) * 34;
    const float* s1 = pws + (((size_t)gw * 2 + 1) * 16 + tl) * 34;
    const float m0 = s0[0], l0 = s0[1], m1 = s1[0], l1 = s1[1];
    const float mn = fmaxf(m0, m1);
    const float c0 = exp2_fast(m0 - mn);        // empty seg (m=-1e30) -> 0
    const float c1 = exp2_fast(m1 - mn);
    const float inv = 1.0f / (0.8f * (l0 * c0 + l1 * c1));

    const float4 a0 = *reinterpret_cast<const float4*>(s0 + 2 + 4 * g);
    const float4 b0 = *reinterpret_cast<const float4*>(s1 + 2 + 4 * g);
    const float4 a1 = *reinterpret_cast<const float4*>(s0 + 18 + 4 * g);
    const float4 b1 = *reinterpret_cast<const float4*>(s1 + 18 + 4 * g);

    float* orow = out + (((size_t)b * TTN) + tile * 32 + th * 16 + tl) * CCH;
    *reinterpret_cast<float4*>(orow + 4 * g) = make_float4(
        (a0.x * c0 + b0.x * c1) * inv, (a0.y * c0 + b0.y * c1) * inv,
        (a0.z * c0 + b0.z * c1) * inv, (a0.w * c0 + b0.w * c1) * inv);
    *reinterpret_cast<float4*>(orow + 16 + 4 * g) = make_float4(
        (a1.x * c0 + b1.x * c1) * inv, (a1.y * c0 + b1.y * c1) * inv,
        (a1.z * c0 + b1.z * c1) * inv, (a1.w * c0 + b1.w * c1) * inv);
}

extern "C" void kernel_launch(void* const* d_in, const int* in_sizes, int n_in,
                              void* d_out, int out_size, void* d_ws, size_t ws_size,
                              hipStream_t stream) {
    const float* x  = (const float*)d_in[0];
    const float* Wq = (const float*)d_in[1];
    const float* Wk = (const float*)d_in[2];
    const float* Wv = (const float*)d_in[3];
    float* outp = (float*)d_out;

    // workspace: Qf 4MiB | Kb 2MiB | Vt 2MiB | partials ~8.9MiB
    float*    Qf  = (float*)d_ws;
    uint16_t* Kb  = (uint16_t*)((char*)d_ws + 4194304);
    uint16_t* Vt  = (uint16_t*)((char*)d_ws + 6291456);
    float*    pws = (float*)((char*)d_ws + 8388608);

    proj_qkv<<<(BB * TTN) / 256, 256, 0, stream>>>(x, Wq, Wk, Wv, Qf, Kb, Vt);
    attn_mfma<<<2048, 256, 0, stream>>>(Qf, Kb, Vt, pws);
    merge_out<<<512, 256, 0, stream>>>(pws, outp);
}